// Round 2
// baseline (3547.851 us; speedup 1.0000x reference)
//
#include <hip/hip_runtime.h>
#include <hip/hip_bf16.h>

#define DIMN 1024
#define IMG_H 512
#define IMG_W 1408
#define CROPN 224
#define NCAM 6
#define NBOXB 32
#define NBATCH 2
#define NBOX 64            // NBATCH*NBOXB
#define NIMG 384           // NBOX*NCAM

typedef __hip_bfloat16 bf16;

__device__ __forceinline__ float b2f(bf16 x) { return __bfloat162float(x); }
__device__ __forceinline__ bf16 f2b(float x) { return __float2bfloat16(x); }
__device__ __forceinline__ float us2f(unsigned short u) {
  union { unsigned int i; float f; } v; v.i = ((unsigned int)u) << 16; return v.f;
}

// ---------------- prep: transposes ----------------
// in: [OC][K] f32 -> out: [K][OC] f32
__global__ void k_transpose_f(const float* __restrict__ w, float* __restrict__ wt, int OC, int K) {
  int idx = blockIdx.x * 256 + threadIdx.x;
  if (idx >= OC * K) return;
  int k = idx / OC, oc = idx % OC;
  wt[idx] = w[(size_t)oc * K + k];
}
// in: [OC][K] f32 -> out: [K][OC] bf16
__global__ void k_transpose_fb(const float* __restrict__ w, bf16* __restrict__ wt, int OC, int K) {
  int idx = blockIdx.x * 256 + threadIdx.x;
  if (idx >= OC * K) return;
  int k = idx / OC, oc = idx % OC;
  wt[idx] = f2b(w[(size_t)oc * K + k]);
}

// ---------------- projection + theta ----------------
__global__ void k_proj(const float* __restrict__ boxes, const float* __restrict__ la_m,
                       const float* __restrict__ l2i, const float* __restrict__ aug,
                       const float* __restrict__ tw, const float* __restrict__ tb,
                       float* __restrict__ theta_out, int* __restrict__ valid_out) {
  int t = threadIdx.x;
  if (t >= NIMG) return;
  int n = t / NCAM, cam = t % NCAM;
  int b = n / NBOXB, nb = n % NBOXB;

  float la[4][4];
  for (int r = 0; r < 4; r++)
    for (int c = 0; c < 4; c++) la[r][c] = la_m[b * 16 + r * 4 + c];
  float a00=la[0][0],a01=la[0][1],a02=la[0][2];
  float a10=la[1][0],a11=la[1][1],a12=la[1][2];
  float a20=la[2][0],a21=la[2][1],a22=la[2][2];
  float c00 =  a11*a22 - a12*a21;
  float c01 = -(a10*a22 - a12*a20);
  float c02 =  a10*a21 - a11*a20;
  float det = a00*c00 + a01*c01 + a02*c02;
  float id = 1.0f / det;
  float inv[3][3];
  inv[0][0] = c00*id;                 inv[0][1] = -(a01*a22-a02*a21)*id;  inv[0][2] =  (a01*a12-a02*a11)*id;
  inv[1][0] = c01*id;                 inv[1][1] =  (a00*a22-a02*a20)*id;  inv[1][2] = -(a00*a12-a02*a10)*id;
  inv[2][0] = c02*id;                 inv[2][1] = -(a00*a21-a01*a20)*id;  inv[2][2] =  (a00*a11-a01*a10)*id;

  float bx[9];
  for (int i = 0; i < 9; i++) bx[i] = boxes[(b * NBOXB + nb) * 9 + i];
  float c0[3] = { bx[0]-la[0][3], bx[1]-la[1][3], bx[2]-la[2][3] };
  float c1[3];
  for (int r = 0; r < 3; r++) c1[r] = inv[r][0]*c0[0] + inv[r][1]*c0[1] + inv[r][2]*c0[2];

  const float* M = l2i + (size_t)(b * NCAM + cam) * 16;
  float p[3];
  for (int r = 0; r < 3; r++)
    p[r] = M[r*4+0]*c1[0] + M[r*4+1]*c1[1] + M[r*4+2]*c1[2] + M[r*4+3];
  float z = fminf(fmaxf(p[2], 1e-5f), 100000.0f);
  float x = p[0] / z, y = p[1] / z;
  const float* A = aug + (size_t)(b * NCAM + cam) * 16;
  float u = A[0]*x + A[1]*y + A[2]*z + A[3];
  float v = A[4]*x + A[5]*y + A[6]*z + A[7];

  int on = (v < (float)IMG_H) && (v >= 0.0f) && (u < (float)IMG_W) && (u >= 0.0f);
  float ty = v / (float)IMG_H * 2.0f - 1.0f;
  float tx = u / (float)IMG_W * 2.0f - 1.0f;

  float s[4];
  for (int j = 0; j < 4; j++) {
    float acc = tb[j];
    for (int i = 0; i < 9; i++) acc += tw[j * 9 + i] * bx[i];
    s[j] = tanhf(acc);
  }
  float* o = theta_out + t * 6;
  o[0] = s[0]; o[1] = s[1]; o[2] = tx;
  o[3] = s[2]; o[4] = s[3]; o[5] = ty;
  valid_out[t] = on;
}

// ---------------- crop sampling ----------------
__global__ __launch_bounds__(256) void k_sample(const float* __restrict__ imgs,
                                                const float* __restrict__ theta,
                                                bf16* __restrict__ crops) {
  int idx = blockIdx.x * 256 + threadIdx.x;   // NIMG*224*224 exactly
  int i = idx / (CROPN * CROPN);
  int rem = idx - i * (CROPN * CROPN);
  int yy = rem / CROPN, xx = rem % CROPN;
  const float* th = theta + i * 6;
  float gx = (2.0f * xx + 1.0f) / (float)CROPN - 1.0f;
  float gy = (2.0f * yy + 1.0f) / (float)CROPN - 1.0f;
  float grid_x = th[0]*gx + th[1]*gy + th[2];
  float grid_y = th[3]*gx + th[4]*gy + th[5];
  float ix = ((grid_x + 1.0f) * (float)IMG_W - 1.0f) * 0.5f;
  float iy = ((grid_y + 1.0f) * (float)IMG_H - 1.0f) * 0.5f;
  float x0 = floorf(ix), y0 = floorf(iy);
  float wx = ix - x0, wy = iy - y0;
  int cam = i % NCAM, b = i / (NBOXB * NCAM);
  const float* base = imgs + (size_t)(b * NCAM + cam) * 3 * IMG_H * IMG_W;

  float xf[2] = { x0, x0 + 1.0f };
  float yf[2] = { y0, y0 + 1.0f };
  float wxa[2] = { 1.0f - wx, wx };
  float wya[2] = { 1.0f - wy, wy };
  int   xi[2], yi[2], vx[2], vy[2];
  for (int j = 0; j < 2; j++) {
    vx[j] = (xf[j] >= 0.0f) && (xf[j] <= (float)(IMG_W - 1));
    vy[j] = (yf[j] >= 0.0f) && (yf[j] <= (float)(IMG_H - 1));
    xi[j] = (int)fminf(fmaxf(xf[j], 0.0f), (float)(IMG_W - 1));
    yi[j] = (int)fminf(fmaxf(yf[j], 0.0f), (float)(IMG_H - 1));
  }
  for (int ch = 0; ch < 3; ch++) {
    const float* cp = base + (size_t)ch * IMG_H * IMG_W;
    float r = 0.0f;
    for (int jy = 0; jy < 2; jy++)
      for (int jx = 0; jx < 2; jx++) {
        float val = (vx[jx] && vy[jy]) ? cp[yi[jy] * IMG_W + xi[jx]] : 0.0f;
        r += val * wxa[jx] * wya[jy];
      }
    crops[((size_t)i * 3 + ch) * (CROPN * CROPN) + rem] = f2b(r);
  }
}

// ---------------- conv1: 3->64, 7x7 s4, pad before=1, relu ----------------
__global__ __launch_bounds__(256) void k_conv1(const bf16* __restrict__ crops,
                                               const float* __restrict__ wt1, // [147][64]
                                               bf16* __restrict__ out1) {
  __shared__ float s_in[3][7][228];
  __shared__ float s_w[147][64];
  int blk = blockIdx.x;               // 384*56
  int i = blk / 56, oh = blk % 56;
  int tid = threadIdx.x;
  for (int idx = tid; idx < 147 * 64; idx += 256) ((float*)s_w)[idx] = wt1[idx];
  for (int idx = tid; idx < 3 * 7 * 228; idx += 256) {
    int ch = idx / (7 * 228);
    int r = (idx / 228) % 7;
    int c = idx % 228;
    int ih = oh * 4 + r - 1;
    int iw = c - 1;
    float v = 0.0f;
    if (ih >= 0 && ih < 224 && iw >= 0 && iw < 224)
      v = b2f(crops[((size_t)i * 3 + ch) * (224 * 224) + ih * 224 + iw]);
    s_in[ch][r][c] = v;
  }
  __syncthreads();
  if (tid >= 224) return;
  int owg = tid / 16, ocg = tid % 16;
  int oc0 = ocg * 4, ow0 = owg * 4;
  float acc[4][4] = {};
  for (int ch = 0; ch < 3; ch++) {
    #pragma unroll
    for (int kh = 0; kh < 7; kh++) {
      const float* rp = &s_in[ch][kh][ow0 * 4];
      float inr[20];
      #pragma unroll
      for (int q = 0; q < 5; q++) {
        float4 tv = *(const float4*)(rp + q * 4);
        inr[q*4+0] = tv.x; inr[q*4+1] = tv.y; inr[q*4+2] = tv.z; inr[q*4+3] = tv.w;
      }
      #pragma unroll
      for (int kw = 0; kw < 7; kw++) {
        float4 wv = *(const float4*)(&s_w[(ch * 7 + kh) * 7 + kw][oc0]);
        #pragma unroll
        for (int j = 0; j < 4; j++) {
          float x = inr[j * 4 + kw];
          acc[j][0] += x * wv.x; acc[j][1] += x * wv.y;
          acc[j][2] += x * wv.z; acc[j][3] += x * wv.w;
        }
      }
    }
  }
  #pragma unroll
  for (int j = 0; j < 4; j++)
    #pragma unroll
    for (int l = 0; l < 4; l++) {
      float v = fmaxf(acc[j][l], 0.0f);
      out1[(((size_t)i * 64 + oc0 + l) * 56 + oh) * 56 + (ow0 + j)] = f2b(v);
    }
}

// ---------------- conv2: 64->256, 3x3 s4, pad 0, relu ----------------
__global__ __launch_bounds__(256) void k_conv2(const bf16* __restrict__ in1,
                                               const float* __restrict__ wt2, // [576][256]
                                               bf16* __restrict__ out2) {
  __shared__ float s_in[64][3][64];
  int blk = blockIdx.x;               // 384*14
  int i = blk / 14, oh = blk % 14;
  int tid = threadIdx.x;
  for (int idx = tid; idx < 64 * 3 * 64; idx += 256) {
    int ic = idx / 192;
    int r = (idx / 64) % 3;
    int c = idx % 64;
    float v = 0.0f;
    if (c < 56) {
      int ih = oh * 4 + r;
      v = b2f(in1[(((size_t)i * 64 + ic) * 56 + ih) * 56 + c]);
    }
    s_in[ic][r][c] = v;
  }
  __syncthreads();
  int ocg = tid & 63, owg = tid >> 6;
  int oc0 = ocg * 4, ow0 = owg * 4;
  float acc[4][4] = {};
  for (int ic = 0; ic < 64; ic++) {
    #pragma unroll
    for (int r = 0; r < 3; r++) {
      const float* rp = &s_in[ic][r][owg * 16];
      float inr[16];
      #pragma unroll
      for (int q = 0; q < 4; q++) {
        float4 tv = *(const float4*)(rp + q * 4);
        inr[q*4+0] = tv.x; inr[q*4+1] = tv.y; inr[q*4+2] = tv.z; inr[q*4+3] = tv.w;
      }
      #pragma unroll
      for (int kw = 0; kw < 3; kw++) {
        int k = ic * 9 + r * 3 + kw;
        float4 wv = *(const float4*)(wt2 + (size_t)k * 256 + oc0);
        #pragma unroll
        for (int j = 0; j < 4; j++) {
          float x = inr[j * 4 + kw];
          acc[j][0] += x * wv.x; acc[j][1] += x * wv.y;
          acc[j][2] += x * wv.z; acc[j][3] += x * wv.w;
        }
      }
    }
  }
  #pragma unroll
  for (int j = 0; j < 4; j++) {
    int ow = ow0 + j;
    if (ow < 14) {
      #pragma unroll
      for (int l = 0; l < 4; l++) {
        float v = fmaxf(acc[j][l], 0.0f);
        out2[(((size_t)i * 256 + oc0 + l) * 14 + oh) * 14 + ow] = f2b(v);
      }
    }
  }
}

// ---------------- conv3: 256->1024, 3x3 s2, pad after=1, relu -> (i, p, oc) f32 ----------------
__global__ __launch_bounds__(256) void k_conv3(const bf16* __restrict__ in2,
                                               const unsigned short* __restrict__ wt3, // [2304][1024] bf16
                                               float* __restrict__ out3) {
  __shared__ float s_in[256][3][16];
  int blk = blockIdx.x;               // 384*7
  int i = blk / 7, oh = blk % 7;
  int tid = threadIdx.x;
  for (int idx = tid; idx < 256 * 48; idx += 256) {
    int ic = idx / 48;
    int r = (idx / 16) % 3;
    int c = idx & 15;
    int ih = oh * 2 + r;
    float v = 0.0f;
    if (ih < 14 && c < 14)
      v = b2f(in2[(((size_t)i * 256 + ic) * 14 + ih) * 14 + c]);
    s_in[ic][r][c] = v;
  }
  __syncthreads();
  int oc0 = tid * 4;
  float acc[7][4] = {};
  for (int ic = 0; ic < 256; ic++) {
    #pragma unroll
    for (int r = 0; r < 3; r++) {
      const float* rp = &s_in[ic][r][0];
      float inr[16];
      #pragma unroll
      for (int q = 0; q < 4; q++) {
        float4 tv = *(const float4*)(rp + q * 4);
        inr[q*4+0] = tv.x; inr[q*4+1] = tv.y; inr[q*4+2] = tv.z; inr[q*4+3] = tv.w;
      }
      #pragma unroll
      for (int kw = 0; kw < 3; kw++) {
        int k = ic * 9 + r * 3 + kw;
        ushort4 wu = *(const ushort4*)(wt3 + (size_t)k * 1024 + oc0);
        float w0 = us2f(wu.x), w1 = us2f(wu.y), w2 = us2f(wu.z), w3 = us2f(wu.w);
        #pragma unroll
        for (int ow = 0; ow < 7; ow++) {
          float x = inr[ow * 2 + kw];
          acc[ow][0] += x * w0; acc[ow][1] += x * w1;
          acc[ow][2] += x * w2; acc[ow][3] += x * w3;
        }
      }
    }
  }
  #pragma unroll
  for (int ow = 0; ow < 7; ow++) {
    float* op = out3 + ((size_t)i * 49 + oh * 7 + ow) * DIMN + oc0;
    #pragma unroll
    for (int l = 0; l < 4; l++) op[l] = fmaxf(acc[ow][l], 0.0f);
  }
}

// ---------------- tokens: mean + concat + pos ----------------
__global__ __launch_bounds__(256) void k_tok(const float* __restrict__ h,   // (384,49,1024)
                                             const float* __restrict__ pos, // (50,1024)
                                             float* __restrict__ tok) {     // (384,50,1024)
  int blk = blockIdx.x;               // 384*50
  int i = blk / 50, t = blk % 50;
  int d = threadIdx.x * 4;
  float4 val;
  if (t == 0) {
    float sx = 0, sy = 0, sz = 0, sw = 0;
    for (int p = 0; p < 49; p++) {
      float4 v = *(const float4*)(h + ((size_t)i * 49 + p) * DIMN + d);
      sx += v.x; sy += v.y; sz += v.z; sw += v.w;
    }
    const float inv49 = 1.0f / 49.0f;
    val.x = sx * inv49; val.y = sy * inv49; val.z = sz * inv49; val.w = sw * inv49;
  } else {
    val = *(const float4*)(h + ((size_t)i * 49 + (t - 1)) * DIMN + d);
  }
  float4 pe = *(const float4*)(pos + (size_t)t * DIMN + d);
  float4 o; o.x = val.x + pe.x; o.y = val.y + pe.y; o.z = val.z + pe.z; o.w = val.w + pe.w;
  *(float4*)(tok + ((size_t)i * 50 + t) * DIMN + d) = o;
}

// ---------------- generic per-image matvec: out[i,:] = vec[i,:] @ M  (M: [1024][1024]) ----------------
__global__ __launch_bounds__(256) void k_matvec(const float* __restrict__ vecs, int vstride,
                                                const float* __restrict__ M,
                                                float* __restrict__ out) {
  __shared__ float s_v[DIMN];
  int i = blockIdx.x;
  const float* v = vecs + (size_t)i * vstride;
  for (int e = threadIdx.x; e < DIMN; e += 256) s_v[e] = v[e];
  __syncthreads();
  int d0 = threadIdx.x * 4;
  float ax = 0, ay = 0, az = 0, aw = 0;
  for (int e = 0; e < DIMN; e++) {
    float x = s_v[e];
    float4 w = *(const float4*)(M + (size_t)e * DIMN + d0);
    ax += x * w.x; ay += x * w.y; az += x * w.z; aw += x * w.w;
  }
  float4 o; o.x = ax; o.y = ay; o.z = az; o.w = aw;
  *(float4*)(out + (size_t)i * DIMN + d0) = o;
}

// ---------------- scores + softmax + attn-weighted token mix ----------------
__global__ __launch_bounds__(256) void k_attn(const float* __restrict__ tok,
                                              const float* __restrict__ a1,
                                              float* __restrict__ tvec) {
  __shared__ float s_a[DIMN];
  __shared__ float s_sc[50];
  __shared__ float s_at[50];
  int i = blockIdx.x;
  for (int e = threadIdx.x; e < DIMN; e += 256) s_a[e] = a1[(size_t)i * DIMN + e];
  __syncthreads();
  int wave = threadIdx.x >> 6, lane = threadIdx.x & 63;
  for (int t = wave; t < 50; t += 4) {
    const float* tr = tok + ((size_t)i * 50 + t) * DIMN;
    float p = 0.0f;
    for (int m = 0; m < 16; m++) {
      int e = lane + m * 64;
      p += tr[e] * s_a[e];
    }
    for (int off = 32; off > 0; off >>= 1) p += __shfl_down(p, off, 64);
    if (lane == 0) s_sc[t] = p * 0.03125f;  // DIM^-0.5
  }
  __syncthreads();
  if (threadIdx.x == 0) {
    float mx = s_sc[0];
    for (int t = 1; t < 50; t++) mx = fmaxf(mx, s_sc[t]);
    float sum = 0.0f;
    for (int t = 0; t < 50; t++) { float ex = expf(s_sc[t] - mx); s_at[t] = ex; sum += ex; }
    float inv = 1.0f / sum;
    for (int t = 0; t < 50; t++) s_at[t] *= inv;
  }
  __syncthreads();
  int d0 = threadIdx.x * 4;
  float ax = 0, ay = 0, az = 0, aw = 0;
  for (int t = 0; t < 50; t++) {
    float at = s_at[t];
    float4 tv = *(const float4*)(tok + ((size_t)i * 50 + t) * DIMN + d0);
    ax += at * tv.x; ay += at * tv.y; az += at * tv.z; aw += at * tv.w;
  }
  float4 o; o.x = ax; o.y = ay; o.z = az; o.w = aw;
  *(float4*)(tvec + (size_t)i * DIMN + d0) = o;
}

// ---------------- final momentum merge ----------------
__global__ __launch_bounds__(256) void k_final(const float* __restrict__ emb,
                                               const int* __restrict__ valid,
                                               const float* __restrict__ bdd,
                                               const float* __restrict__ momp,
                                               float* __restrict__ out) {
  int n = blockIdx.x;
  int d0 = threadIdx.x * 4;
  float mom = momp[0];
  float e[4];
  #pragma unroll
  for (int j = 0; j < 4; j++) e[j] = bdd[d0 + j];
  const int order[6] = {2, 0, 1, 5, 3, 4};
  #pragma unroll
  for (int s = 0; s < 6; s++) {
    int c = order[s];
    int i = n * NCAM + c;
    if (valid[i]) {
      const float* er = emb + (size_t)i * DIMN + d0;
      #pragma unroll
      for (int j = 0; j < 4; j++) e[j] = mom * e[j] + (1.0f - mom) * er[j];
    }
  }
  #pragma unroll
  for (int j = 0; j < 4; j++) out[(size_t)n * DIMN + d0 + j] = e[j];
}

extern "C" void kernel_launch(void* const* d_in, const int* in_sizes, int n_in,
                              void* d_out, int out_size, void* d_ws, size_t ws_size,
                              hipStream_t stream) {
  const float* in_cam = (const float*)d_in[0];
  const float* in_box = (const float*)d_in[1];
  const float* in_aug = (const float*)d_in[2];
  const float* in_la  = (const float*)d_in[3];
  const float* in_l2i = (const float*)d_in[4];
  const float* in_mom = (const float*)d_in[5];
  const float* in_bdd = (const float*)d_in[6];
  const float* in_tw  = (const float*)d_in[7];
  const float* in_tb  = (const float*)d_in[8];
  const float* in_c1  = (const float*)d_in[9];
  const float* in_c2  = (const float*)d_in[10];
  const float* in_c3  = (const float*)d_in[11];
  const float* in_pe  = (const float*)d_in[12];
  const float* in_wq  = (const float*)d_in[13];
  const float* in_wk  = (const float*)d_in[14];
  const float* in_wv  = (const float*)d_in[15];
  const float* in_wo  = (const float*)d_in[16];

  char* base = (char*)d_ws;
  size_t off = 0;
  auto carve = [&](size_t bytes) -> char* {
    char* p = base + off;
    off += (bytes + 255) & ~(size_t)255;
    return p;
  };
  float* theta   = (float*)carve((size_t)NIMG * 6 * 4);
  int*   valid   = (int*)carve((size_t)NIMG * 4);
  float* qbuf    = (float*)carve((size_t)NIMG * DIMN * 4);
  float* a1buf   = (float*)carve((size_t)NIMG * DIMN * 4);
  float* tvbuf   = (float*)carve((size_t)NIMG * DIMN * 4);
  float* ctxbuf  = (float*)carve((size_t)NIMG * DIMN * 4);
  float* embbuf  = (float*)carve((size_t)NIMG * DIMN * 4);
  float* wkT_f   = (float*)carve((size_t)DIMN * DIMN * 4);
  float* wt1     = (float*)carve((size_t)147 * 64 * 4);
  float* wt2     = (float*)carve((size_t)576 * 256 * 4);
  bf16*  wt3     = (bf16*)carve((size_t)2304 * 1024 * 2);
  bf16*  conv2o  = (bf16*)carve((size_t)NIMG * 256 * 196 * 2);
  char*  RA      = carve((size_t)NIMG * 3 * CROPN * CROPN * 2);      // crops bf16 / conv3_out f32
  char*  RB      = carve((size_t)NIMG * 64 * 56 * 56 * 2);           // conv1_out bf16 / tok f32
  bf16*  crops   = (bf16*)RA;
  float* conv3o  = (float*)RA;
  bf16*  conv1o  = (bf16*)RB;
  float* tok     = (float*)RB;

  int n;
  n = DIMN * DIMN;
  k_transpose_f<<<(n + 255) / 256, 256, 0, stream>>>(in_wk, wkT_f, DIMN, DIMN);
  n = 64 * 147;
  k_transpose_f<<<(n + 255) / 256, 256, 0, stream>>>(in_c1, wt1, 64, 147);
  n = 256 * 576;
  k_transpose_f<<<(n + 255) / 256, 256, 0, stream>>>(in_c2, wt2, 256, 576);
  n = 1024 * 2304;
  k_transpose_fb<<<(n + 255) / 256, 256, 0, stream>>>(in_c3, wt3, 1024, 2304);

  k_proj<<<1, 384, 0, stream>>>(in_box, in_la, in_l2i, in_aug, in_tw, in_tb, theta, valid);
  k_sample<<<(NIMG * CROPN * CROPN) / 256, 256, 0, stream>>>(in_cam, theta, crops);
  k_conv1<<<NIMG * 56, 256, 0, stream>>>(crops, wt1, conv1o);
  k_conv2<<<NIMG * 14, 256, 0, stream>>>(conv1o, wt2, conv2o);
  k_conv3<<<NIMG * 7, 256, 0, stream>>>(conv2o, (const unsigned short*)wt3, conv3o);
  k_tok<<<NIMG * 50, 256, 0, stream>>>(conv3o, in_pe, tok);
  k_matvec<<<NIMG, 256, 0, stream>>>(tok, 50 * DIMN, in_wq, qbuf);      // q = tok0 @ wq
  k_matvec<<<NIMG, 256, 0, stream>>>(qbuf, DIMN, wkT_f, a1buf);         // a1 = wk @ q
  k_attn<<<NIMG, 256, 0, stream>>>(tok, a1buf, tvbuf);                  // softmax + mix
  k_matvec<<<NIMG, 256, 0, stream>>>(tvbuf, DIMN, in_wv, ctxbuf);       // ctx = tvec @ wv
  k_matvec<<<NIMG, 256, 0, stream>>>(ctxbuf, DIMN, in_wo, embbuf);      // emb = ctx @ wo
  k_final<<<NBOX, 256, 0, stream>>>(embbuf, valid, in_bdd, in_mom, (float*)d_out);
}

// Round 3
// 1668.013 us; speedup vs baseline: 2.1270x; 2.1270x over previous
//
#include <hip/hip_runtime.h>
#include <hip/hip_bf16.h>

#define DIMN 1024
#define IMG_H 512
#define IMG_W 1408
#define CROPN 224
#define NCAM 6
#define NBOXB 32
#define NBOX 64            // NBATCH*NBOXB
#define NIMG 384           // NBOX*NCAM

typedef __hip_bfloat16 bf16;
typedef float f32x4 __attribute__((ext_vector_type(4)));
typedef short bf16x8 __attribute__((ext_vector_type(8)));

__device__ __forceinline__ float b2f(bf16 x) { return __bfloat162float(x); }
__device__ __forceinline__ bf16 f2b(float x) { return __float2bfloat16(x); }
__device__ __forceinline__ unsigned short f2us(float x) {
  bf16 h = __float2bfloat16(x);
  return *(unsigned short*)&h;
}

// ---------------- prep ----------------
// wk [OC][K] f32 -> [K][OC] f32
__global__ void k_transpose_f(const float* __restrict__ w, float* __restrict__ wt, int OC, int K) {
  int idx = blockIdx.x * 256 + threadIdx.x;
  if (idx >= OC * K) return;
  int k = idx / OC, oc = idx % OC;
  wt[idx] = w[(size_t)oc * K + k];
}
// flat f32 -> bf16 (weights already in [oc][k] order)
__global__ void k_castb(const float* __restrict__ in, unsigned short* __restrict__ out, int n) {
  int i = blockIdx.x * 256 + threadIdx.x;
  if (i < n) out[i] = f2us(in[i]);
}
// conv1 weights: [64][147] f32 -> [64][160] bf16 zero-padded
__global__ void k_w1pad(const float* __restrict__ in, unsigned short* __restrict__ out) {
  int idx = blockIdx.x * 256 + threadIdx.x;
  if (idx >= 64 * 160) return;
  int oc = idx / 160, k = idx % 160;
  out[idx] = (k < 147) ? f2us(in[oc * 147 + k]) : (unsigned short)0;
}

// ---------------- projection + theta ----------------
__global__ void k_proj(const float* __restrict__ boxes, const float* __restrict__ la_m,
                       const float* __restrict__ l2i, const float* __restrict__ aug,
                       const float* __restrict__ tw, const float* __restrict__ tb,
                       float* __restrict__ theta_out, int* __restrict__ valid_out) {
  int t = threadIdx.x;
  if (t >= NIMG) return;
  int n = t / NCAM, cam = t % NCAM;
  int b = n / NBOXB, nb = n % NBOXB;

  float la[4][4];
  for (int r = 0; r < 4; r++)
    for (int c = 0; c < 4; c++) la[r][c] = la_m[b * 16 + r * 4 + c];
  float a00=la[0][0],a01=la[0][1],a02=la[0][2];
  float a10=la[1][0],a11=la[1][1],a12=la[1][2];
  float a20=la[2][0],a21=la[2][1],a22=la[2][2];
  float c00 =  a11*a22 - a12*a21;
  float c01 = -(a10*a22 - a12*a20);
  float c02 =  a10*a21 - a11*a20;
  float det = a00*c00 + a01*c01 + a02*c02;
  float id = 1.0f / det;
  float inv[3][3];
  inv[0][0] = c00*id;                 inv[0][1] = -(a01*a22-a02*a21)*id;  inv[0][2] =  (a01*a12-a02*a11)*id;
  inv[1][0] = c01*id;                 inv[1][1] =  (a00*a22-a02*a20)*id;  inv[1][2] = -(a00*a12-a02*a10)*id;
  inv[2][0] = c02*id;                 inv[2][1] = -(a00*a21-a01*a20)*id;  inv[2][2] =  (a00*a11-a01*a10)*id;

  float bx[9];
  for (int i = 0; i < 9; i++) bx[i] = boxes[(b * NBOXB + nb) * 9 + i];
  float c0[3] = { bx[0]-la[0][3], bx[1]-la[1][3], bx[2]-la[2][3] };
  float c1[3];
  for (int r = 0; r < 3; r++) c1[r] = inv[r][0]*c0[0] + inv[r][1]*c0[1] + inv[r][2]*c0[2];

  const float* M = l2i + (size_t)(b * NCAM + cam) * 16;
  float p[3];
  for (int r = 0; r < 3; r++)
    p[r] = M[r*4+0]*c1[0] + M[r*4+1]*c1[1] + M[r*4+2]*c1[2] + M[r*4+3];
  float z = fminf(fmaxf(p[2], 1e-5f), 100000.0f);
  float x = p[0] / z, y = p[1] / z;
  const float* A = aug + (size_t)(b * NCAM + cam) * 16;
  float u = A[0]*x + A[1]*y + A[2]*z + A[3];
  float v = A[4]*x + A[5]*y + A[6]*z + A[7];

  int on = (v < (float)IMG_H) && (v >= 0.0f) && (u < (float)IMG_W) && (u >= 0.0f);
  float ty = v / (float)IMG_H * 2.0f - 1.0f;
  float tx = u / (float)IMG_W * 2.0f - 1.0f;

  float s[4];
  for (int j = 0; j < 4; j++) {
    float acc = tb[j];
    for (int i = 0; i < 9; i++) acc += tw[j * 9 + i] * bx[i];
    s[j] = tanhf(acc);
  }
  float* o = theta_out + t * 6;
  o[0] = s[0]; o[1] = s[1]; o[2] = tx;
  o[3] = s[2]; o[4] = s[3]; o[5] = ty;
  valid_out[t] = on;
}

// ---------------- crop sampling ----------------
__global__ __launch_bounds__(256) void k_sample(const float* __restrict__ imgs,
                                                const float* __restrict__ theta,
                                                bf16* __restrict__ crops) {
  int idx = blockIdx.x * 256 + threadIdx.x;   // NIMG*224*224 exactly
  int i = idx / (CROPN * CROPN);
  int rem = idx - i * (CROPN * CROPN);
  int yy = rem / CROPN, xx = rem % CROPN;
  const float* th = theta + i * 6;
  float gx = (2.0f * xx + 1.0f) / (float)CROPN - 1.0f;
  float gy = (2.0f * yy + 1.0f) / (float)CROPN - 1.0f;
  float grid_x = th[0]*gx + th[1]*gy + th[2];
  float grid_y = th[3]*gx + th[4]*gy + th[5];
  float ix = ((grid_x + 1.0f) * (float)IMG_W - 1.0f) * 0.5f;
  float iy = ((grid_y + 1.0f) * (float)IMG_H - 1.0f) * 0.5f;
  float x0 = floorf(ix), y0 = floorf(iy);
  float wx = ix - x0, wy = iy - y0;
  int cam = i % NCAM, b = i / (NBOXB * NCAM);
  const float* base = imgs + (size_t)(b * NCAM + cam) * 3 * IMG_H * IMG_W;

  float xf[2] = { x0, x0 + 1.0f };
  float yf[2] = { y0, y0 + 1.0f };
  float wxa[2] = { 1.0f - wx, wx };
  float wya[2] = { 1.0f - wy, wy };
  int   xi[2], yi[2], vx[2], vy[2];
  for (int j = 0; j < 2; j++) {
    vx[j] = (xf[j] >= 0.0f) && (xf[j] <= (float)(IMG_W - 1));
    vy[j] = (yf[j] >= 0.0f) && (yf[j] <= (float)(IMG_H - 1));
    xi[j] = (int)fminf(fmaxf(xf[j], 0.0f), (float)(IMG_W - 1));
    yi[j] = (int)fminf(fmaxf(yf[j], 0.0f), (float)(IMG_H - 1));
  }
  for (int ch = 0; ch < 3; ch++) {
    const float* cp = base + (size_t)ch * IMG_H * IMG_W;
    float r = 0.0f;
    for (int jy = 0; jy < 2; jy++)
      for (int jx = 0; jx < 2; jx++) {
        float val = (vx[jx] && vy[jy]) ? cp[yi[jy] * IMG_W + xi[jx]] : 0.0f;
        r += val * wxa[jx] * wya[jy];
      }
    crops[((size_t)i * 3 + ch) * (CROPN * CROPN) + rem] = f2b(r);
  }
}

// =========================================================================
// MFMA conv recipe (verified layouts, cdna_hip_programming.md §3):
//   mfma_f32_16x16x32_bf16: A[m=lane&15][k=quad*8+j], B[k=quad*8+j][n=lane&15]
//   D: col(n)=lane&15, row(m)=quad*4+reg
// A-fragments read directly from global bf16 weights [oc][K] (L1/L2-hot).
// B-fragments from LDS im2col tile stored [n][K+pad] (pad => 2-way bank = free).
// =========================================================================

// ---------------- conv1 MFMA: 3->64, 7x7 s4, pad before=1, K=147->160 ----------------
#define SK1 168
__global__ __launch_bounds__(256) void k_conv1m(const unsigned short* __restrict__ crops,
                                                const unsigned short* __restrict__ W1, // [64][160] bf16
                                                bf16* __restrict__ out1) {
  __shared__ unsigned short sX[112 * SK1];   // 37632 B
  int blk = blockIdx.x;                       // 384*28
  int i = blk / 28, rp = blk % 28;
  int oh0 = rp * 2;
  int tid = threadIdx.x;
  for (int idx = tid; idx < 112 * SK1; idx += 256) {
    int n = idx / SK1, k = idx - n * SK1;
    unsigned short v = 0;
    if (k < 147) {
      int ch = k / 49, kr = k - ch * 49;
      int r = kr / 7, kw = kr - r * 7;
      int oh = oh0 + (n / 56), ow = n % 56;
      int ih = oh * 4 + r - 1;
      int iw = ow * 4 + kw - 1;
      if ((unsigned)ih < 224u && (unsigned)iw < 224u)
        v = crops[((size_t)i * 3 + ch) * (224 * 224) + ih * 224 + iw];
    }
    sX[idx] = v;
  }
  __syncthreads();
  int wv = tid >> 6, lane = tid & 63;
  int m = lane & 15, quad = lane >> 4;
  f32x4 acc[7];
  #pragma unroll
  for (int nt = 0; nt < 7; nt++) acc[nt] = (f32x4){0.f, 0.f, 0.f, 0.f};
  const unsigned short* wrow = W1 + (size_t)(wv * 16 + m) * 160;
  #pragma unroll
  for (int kc = 0; kc < 5; kc++) {
    bf16x8 a = *(const bf16x8*)(wrow + kc * 32 + quad * 8);
    #pragma unroll
    for (int nt = 0; nt < 7; nt++) {
      bf16x8 b = *(const bf16x8*)(&sX[(nt * 16 + m) * SK1 + kc * 32 + quad * 8]);
      acc[nt] = __builtin_amdgcn_mfma_f32_16x16x32_bf16(a, b, acc[nt], 0, 0, 0);
    }
  }
  #pragma unroll
  for (int nt = 0; nt < 7; nt++) {
    int n = nt * 16 + m;
    int oh = oh0 + n / 56, ow = n % 56;
    #pragma unroll
    for (int r = 0; r < 4; r++) {
      int oc = wv * 16 + quad * 4 + r;
      out1[(((size_t)i * 64 + oc) * 56 + oh) * 56 + ow] = f2b(fmaxf(acc[nt][r], 0.f));
    }
  }
}

// ---------------- conv2 MFMA: 64->256, 3x3 s4, pad 0, K=576 ----------------
#define SK2 584
__global__ __launch_bounds__(256) void k_conv2m(const unsigned short* __restrict__ in1,
                                                const unsigned short* __restrict__ W2, // [256][576] bf16
                                                bf16* __restrict__ out2) {
  __shared__ unsigned short sX[32 * SK2];    // 37376 B
  int blk = blockIdx.x;                       // 384*7
  int i = blk / 7, rp = blk % 7;
  int oh0 = rp * 2;
  int tid = threadIdx.x;
  for (int idx = tid; idx < 32 * SK2; idx += 256) {
    int n = idx / SK2, k = idx - n * SK2;
    unsigned short v = 0;
    if (n < 28 && k < 576) {
      int ic = k / 9, kr = k - ic * 9;
      int r = kr / 3, kw = kr - r * 3;
      int oh = oh0 + (n / 14), ow = n % 14;
      int ih = oh * 4 + r, iw = ow * 4 + kw;
      v = in1[(((size_t)i * 64 + ic) * 56 + ih) * 56 + iw];
    }
    sX[idx] = v;
  }
  __syncthreads();
  int wv = tid >> 6, lane = tid & 63;
  int m = lane & 15, quad = lane >> 4;
  f32x4 acc[4][2];
  #pragma unroll
  for (int t = 0; t < 4; t++)
    #pragma unroll
    for (int nt = 0; nt < 2; nt++) acc[t][nt] = (f32x4){0.f, 0.f, 0.f, 0.f};
  for (int kc = 0; kc < 18; kc++) {
    int ko = kc * 32 + quad * 8;
    bf16x8 a[4];
    #pragma unroll
    for (int t = 0; t < 4; t++)
      a[t] = *(const bf16x8*)(W2 + (size_t)(wv * 64 + t * 16 + m) * 576 + ko);
    #pragma unroll
    for (int nt = 0; nt < 2; nt++) {
      bf16x8 b = *(const bf16x8*)(&sX[(nt * 16 + m) * SK2 + ko]);
      #pragma unroll
      for (int t = 0; t < 4; t++)
        acc[t][nt] = __builtin_amdgcn_mfma_f32_16x16x32_bf16(a[t], b, acc[t][nt], 0, 0, 0);
    }
  }
  #pragma unroll
  for (int t = 0; t < 4; t++)
    #pragma unroll
    for (int nt = 0; nt < 2; nt++) {
      int n = nt * 16 + m;
      if (n < 28) {
        int oh = oh0 + n / 14, ow = n % 14;
        #pragma unroll
        for (int r = 0; r < 4; r++) {
          int oc = wv * 64 + t * 16 + quad * 4 + r;
          out2[(((size_t)i * 256 + oc) * 14 + oh) * 14 + ow] = f2b(fmaxf(acc[t][nt][r], 0.f));
        }
      }
    }
}

// ---------------- conv3 MFMA: 256->1024, 3x3 s2, pad after=1, K=2304 -> (i,p,oc) f32 ----------------
#define SK3 136
__global__ __launch_bounds__(256) void k_conv3m(const unsigned short* __restrict__ in2,
                                                const unsigned short* __restrict__ W3, // [1024][2304] bf16
                                                float* __restrict__ out3) {
  __shared__ unsigned short sX[64 * SK3];    // 17408 B
  int blk = blockIdx.x;                       // 384*4
  int i = blk / 4, mg = blk % 4;
  int oc_base = mg * 256;
  int tid = threadIdx.x;
  int wv = tid >> 6, lane = tid & 63;
  int m = lane & 15, quad = lane >> 4;
  f32x4 acc[4][4];
  #pragma unroll
  for (int t = 0; t < 4; t++)
    #pragma unroll
    for (int nt = 0; nt < 4; nt++) acc[t][nt] = (f32x4){0.f, 0.f, 0.f, 0.f};

  for (int it = 0; it < 18; it++) {
    int kbase = it * 128;
    __syncthreads();
    for (int idx = tid; idx < 64 * 128; idx += 256) {
      int n = idx >> 7, kk = idx & 127;
      int k = kbase + kk;
      unsigned short v = 0;
      if (n < 49) {
        int ic = k / 9, kr = k - ic * 9;
        int r = kr / 3, kw = kr - r * 3;
        int oh = n / 7, ow = n - oh * 7;
        int ih = oh * 2 + r, iw = ow * 2 + kw;
        if (ih < 14 && iw < 14)
          v = in2[(((size_t)i * 256 + ic) * 14 + ih) * 14 + iw];
      }
      sX[n * SK3 + kk] = v;
    }
    __syncthreads();
    #pragma unroll
    for (int kq = 0; kq < 4; kq++) {
      int ko = kq * 32 + quad * 8;
      bf16x8 a[4];
      #pragma unroll
      for (int t = 0; t < 4; t++)
        a[t] = *(const bf16x8*)(W3 + (size_t)(oc_base + (wv * 4 + t) * 16 + m) * 2304 + kbase + ko);
      #pragma unroll
      for (int nt = 0; nt < 4; nt++) {
        bf16x8 b = *(const bf16x8*)(&sX[(nt * 16 + m) * SK3 + ko]);
        #pragma unroll
        for (int t = 0; t < 4; t++)
          acc[t][nt] = __builtin_amdgcn_mfma_f32_16x16x32_bf16(a[t], b, acc[t][nt], 0, 0, 0);
      }
    }
  }
  #pragma unroll
  for (int t = 0; t < 4; t++)
    #pragma unroll
    for (int nt = 0; nt < 4; nt++) {
      int n = nt * 16 + m;
      if (n < 49) {
        #pragma unroll
        for (int r = 0; r < 4; r++) {
          int oc = oc_base + (wv * 4 + t) * 16 + quad * 4 + r;
          out3[((size_t)i * 49 + n) * DIMN + oc] = fmaxf(acc[t][nt][r], 0.f);
        }
      }
    }
}

// ---------------- tokens: mean + concat + pos ----------------
__global__ __launch_bounds__(256) void k_tok(const float* __restrict__ h,   // (384,49,1024)
                                             const float* __restrict__ pos, // (50,1024)
                                             float* __restrict__ tok) {     // (384,50,1024)
  int blk = blockIdx.x;               // 384*50
  int i = blk / 50, t = blk % 50;
  int d = threadIdx.x * 4;
  float4 val;
  if (t == 0) {
    float sx = 0, sy = 0, sz = 0, sw = 0;
    for (int p = 0; p < 49; p++) {
      float4 v = *(const float4*)(h + ((size_t)i * 49 + p) * DIMN + d);
      sx += v.x; sy += v.y; sz += v.z; sw += v.w;
    }
    const float inv49 = 1.0f / 49.0f;
    val.x = sx * inv49; val.y = sy * inv49; val.z = sz * inv49; val.w = sw * inv49;
  } else {
    val = *(const float4*)(h + ((size_t)i * 49 + (t - 1)) * DIMN + d);
  }
  float4 pe = *(const float4*)(pos + (size_t)t * DIMN + d);
  float4 o; o.x = val.x + pe.x; o.y = val.y + pe.y; o.z = val.z + pe.z; o.w = val.w + pe.w;
  *(float4*)(tok + ((size_t)i * 50 + t) * DIMN + d) = o;
}

// ---------------- generic per-image matvec: out[i,:] = vec[i,:] @ M ----------------
__global__ __launch_bounds__(256) void k_matvec(const float* __restrict__ vecs, int vstride,
                                                const float* __restrict__ M,
                                                float* __restrict__ out) {
  __shared__ float s_v[DIMN];
  int i = blockIdx.x;
  const float* v = vecs + (size_t)i * vstride;
  for (int e = threadIdx.x; e < DIMN; e += 256) s_v[e] = v[e];
  __syncthreads();
  int d0 = threadIdx.x * 4;
  float ax = 0, ay = 0, az = 0, aw = 0;
  for (int e = 0; e < DIMN; e++) {
    float x = s_v[e];
    float4 w = *(const float4*)(M + (size_t)e * DIMN + d0);
    ax += x * w.x; ay += x * w.y; az += x * w.z; aw += x * w.w;
  }
  float4 o; o.x = ax; o.y = ay; o.z = az; o.w = aw;
  *(float4*)(out + (size_t)i * DIMN + d0) = o;
}

// ---------------- scores + softmax + attn-weighted token mix ----------------
__global__ __launch_bounds__(256) void k_attn(const float* __restrict__ tok,
                                              const float* __restrict__ a1,
                                              float* __restrict__ tvec) {
  __shared__ float s_a[DIMN];
  __shared__ float s_sc[50];
  __shared__ float s_at[50];
  int i = blockIdx.x;
  for (int e = threadIdx.x; e < DIMN; e += 256) s_a[e] = a1[(size_t)i * DIMN + e];
  __syncthreads();
  int wave = threadIdx.x >> 6, lane = threadIdx.x & 63;
  for (int t = wave; t < 50; t += 4) {
    const float* tr = tok + ((size_t)i * 50 + t) * DIMN;
    float p = 0.0f;
    for (int mm = 0; mm < 16; mm++) {
      int e = lane + mm * 64;
      p += tr[e] * s_a[e];
    }
    for (int off = 32; off > 0; off >>= 1) p += __shfl_down(p, off, 64);
    if (lane == 0) s_sc[t] = p * 0.03125f;  // DIM^-0.5
  }
  __syncthreads();
  if (threadIdx.x == 0) {
    float mx = s_sc[0];
    for (int t = 1; t < 50; t++) mx = fmaxf(mx, s_sc[t]);
    float sum = 0.0f;
    for (int t = 0; t < 50; t++) { float ex = expf(s_sc[t] - mx); s_at[t] = ex; sum += ex; }
    float inv = 1.0f / sum;
    for (int t = 0; t < 50; t++) s_at[t] *= inv;
  }
  __syncthreads();
  int d0 = threadIdx.x * 4;
  float ax = 0, ay = 0, az = 0, aw = 0;
  for (int t = 0; t < 50; t++) {
    float at = s_at[t];
    float4 tv = *(const float4*)(tok + ((size_t)i * 50 + t) * DIMN + d0);
    ax += at * tv.x; ay += at * tv.y; az += at * tv.z; aw += at * tv.w;
  }
  float4 o; o.x = ax; o.y = ay; o.z = az; o.w = aw;
  *(float4*)(tvec + (size_t)i * DIMN + d0) = o;
}

// ---------------- final momentum merge ----------------
__global__ __launch_bounds__(256) void k_final(const float* __restrict__ emb,
                                               const int* __restrict__ valid,
                                               const float* __restrict__ bdd,
                                               const float* __restrict__ momp,
                                               float* __restrict__ out) {
  int n = blockIdx.x;
  int d0 = threadIdx.x * 4;
  float mom = momp[0];
  float e[4];
  #pragma unroll
  for (int j = 0; j < 4; j++) e[j] = bdd[d0 + j];
  const int order[6] = {2, 0, 1, 5, 3, 4};
  #pragma unroll
  for (int s = 0; s < 6; s++) {
    int c = order[s];
    int i = n * NCAM + c;
    if (valid[i]) {
      const float* er = emb + (size_t)i * DIMN + d0;
      #pragma unroll
      for (int j = 0; j < 4; j++) e[j] = mom * e[j] + (1.0f - mom) * er[j];
    }
  }
  #pragma unroll
  for (int j = 0; j < 4; j++) out[(size_t)n * DIMN + d0 + j] = e[j];
}

extern "C" void kernel_launch(void* const* d_in, const int* in_sizes, int n_in,
                              void* d_out, int out_size, void* d_ws, size_t ws_size,
                              hipStream_t stream) {
  const float* in_cam = (const float*)d_in[0];
  const float* in_box = (const float*)d_in[1];
  const float* in_aug = (const float*)d_in[2];
  const float* in_la  = (const float*)d_in[3];
  const float* in_l2i = (const float*)d_in[4];
  const float* in_mom = (const float*)d_in[5];
  const float* in_bdd = (const float*)d_in[6];
  const float* in_tw  = (const float*)d_in[7];
  const float* in_tb  = (const float*)d_in[8];
  const float* in_c1  = (const float*)d_in[9];
  const float* in_c2  = (const float*)d_in[10];
  const float* in_c3  = (const float*)d_in[11];
  const float* in_pe  = (const float*)d_in[12];
  const float* in_wq  = (const float*)d_in[13];
  const float* in_wk  = (const float*)d_in[14];
  const float* in_wv  = (const float*)d_in[15];
  const float* in_wo  = (const float*)d_in[16];

  char* base = (char*)d_ws;
  size_t off = 0;
  auto carve = [&](size_t bytes) -> char* {
    char* p = base + off;
    off += (bytes + 255) & ~(size_t)255;
    return p;
  };
  float* theta   = (float*)carve((size_t)NIMG * 6 * 4);
  int*   valid   = (int*)carve((size_t)NIMG * 4);
  float* qbuf    = (float*)carve((size_t)NIMG * DIMN * 4);
  float* a1buf   = (float*)carve((size_t)NIMG * DIMN * 4);
  float* tvbuf   = (float*)carve((size_t)NIMG * DIMN * 4);
  float* ctxbuf  = (float*)carve((size_t)NIMG * DIMN * 4);
  float* embbuf  = (float*)carve((size_t)NIMG * DIMN * 4);
  float* wkT_f   = (float*)carve((size_t)DIMN * DIMN * 4);
  unsigned short* W1b = (unsigned short*)carve((size_t)64 * 160 * 2);
  unsigned short* W2b = (unsigned short*)carve((size_t)256 * 576 * 2);
  unsigned short* W3b = (unsigned short*)carve((size_t)1024 * 2304 * 2);
  bf16*  conv2o  = (bf16*)carve((size_t)NIMG * 256 * 196 * 2);
  char*  RA      = carve((size_t)NIMG * 3 * CROPN * CROPN * 2);      // crops bf16 / conv3_out f32
  char*  RB      = carve((size_t)NIMG * 64 * 56 * 56 * 2);           // conv1_out bf16 / tok f32
  bf16*  crops   = (bf16*)RA;
  float* conv3o  = (float*)RA;
  bf16*  conv1o  = (bf16*)RB;
  float* tok     = (float*)RB;

  int n;
  n = DIMN * DIMN;
  k_transpose_f<<<(n + 255) / 256, 256, 0, stream>>>(in_wk, wkT_f, DIMN, DIMN);
  n = 64 * 160;
  k_w1pad<<<(n + 255) / 256, 256, 0, stream>>>(in_c1, W1b);
  n = 256 * 576;
  k_castb<<<(n + 255) / 256, 256, 0, stream>>>(in_c2, W2b, n);
  n = 1024 * 2304;
  k_castb<<<(n + 255) / 256, 256, 0, stream>>>(in_c3, W3b, n);

  k_proj<<<1, 384, 0, stream>>>(in_box, in_la, in_l2i, in_aug, in_tw, in_tb, theta, valid);
  k_sample<<<(NIMG * CROPN * CROPN) / 256, 256, 0, stream>>>(in_cam, theta, crops);
  k_conv1m<<<NIMG * 28, 256, 0, stream>>>((const unsigned short*)crops, W1b, conv1o);
  k_conv2m<<<NIMG * 7, 256, 0, stream>>>((const unsigned short*)conv1o, W2b, conv2o);
  k_conv3m<<<NIMG * 4, 256, 0, stream>>>((const unsigned short*)conv2o, W3b, conv3o);
  k_tok<<<NIMG * 50, 256, 0, stream>>>(conv3o, in_pe, tok);
  k_matvec<<<NIMG, 256, 0, stream>>>(tok, 50 * DIMN, in_wq, qbuf);      // q = tok0 @ wq
  k_matvec<<<NIMG, 256, 0, stream>>>(qbuf, DIMN, wkT_f, a1buf);         // a1 = wk @ q
  k_attn<<<NIMG, 256, 0, stream>>>(tok, a1buf, tvbuf);                  // softmax + mix
  k_matvec<<<NIMG, 256, 0, stream>>>(tvbuf, DIMN, in_wv, ctxbuf);       // ctx = tvec @ wv
  k_matvec<<<NIMG, 256, 0, stream>>>(ctxbuf, DIMN, in_wo, embbuf);      // emb = ctx @ wo
  k_final<<<NBOX, 256, 0, stream>>>(embbuf, valid, in_bdd, in_mom, (float*)d_out);
}

// Round 4
// 1285.145 us; speedup vs baseline: 2.7607x; 1.2979x over previous
//
#include <hip/hip_runtime.h>
#include <hip/hip_bf16.h>

#define DIMN 1024
#define IMG_H 512
#define IMG_W 1408
#define CROPN 224
#define NCAM 6
#define NBOXB 32
#define NBOX 64            // NBATCH*NBOXB
#define NIMG 384           // NBOX*NCAM

typedef __hip_bfloat16 bf16;
typedef unsigned short u16;
typedef float f32x4 __attribute__((ext_vector_type(4)));
typedef short bf16x8 __attribute__((ext_vector_type(8)));
typedef u16 u16x4 __attribute__((ext_vector_type(4)));
typedef u16 u16x8 __attribute__((ext_vector_type(8)));

__device__ __forceinline__ float b2f(bf16 x) { return __bfloat162float(x); }
__device__ __forceinline__ u16 f2us(float x) {
  bf16 h = __float2bfloat16(x);
  return *(u16*)&h;
}
__device__ __forceinline__ bf16x8 as_b(u16x8 x) {
  union { u16x8 u; bf16x8 b; } c; c.u = x; return c.b;
}

// ---------------- prep: weight reorders (K-order = (r,kw),ic  channel-last) ----------------
// conv1 (64,3,7,7) -> W1r[64][224], K = r*32 + kw*4 + ch  (kw<7, ch<3 else 0)
__global__ void k_w1r(const float* __restrict__ in, u16* __restrict__ out) {
  int idx = blockIdx.x * 256 + threadIdx.x;
  if (idx >= 64 * 224) return;
  int oc = idx / 224, t = idx % 224;
  int r = t >> 5, u = t & 31, kw = u >> 2, ch = u & 3;
  out[idx] = (kw < 7 && ch < 3) ? f2us(in[((oc * 3 + ch) * 7 + r) * 7 + kw]) : (u16)0;
}
// conv2 (256,64,3,3) -> W2r[256][576], K = (r*3+kw)*64 + ic
__global__ void k_w2r(const float* __restrict__ in, u16* __restrict__ out) {
  int idx = blockIdx.x * 256 + threadIdx.x;
  if (idx >= 256 * 576) return;
  int oc = idx / 576, t = idx % 576;
  int rk = t >> 6, ic = t & 63, r = rk / 3, kw = rk % 3;
  out[idx] = f2us(in[((oc * 64 + ic) * 3 + r) * 3 + kw]);
}
// conv3 (1024,256,3,3) -> W3r[1024][2304], K = (r*3+kw)*256 + ic
__global__ void k_w3r(const float* __restrict__ in, u16* __restrict__ out) {
  int idx = blockIdx.x * 256 + threadIdx.x;
  if (idx >= 1024 * 2304) return;
  int oc = idx / 2304, t = idx % 2304;
  int rk = t >> 8, ic = t & 255, r = rk / 3, kw = rk % 3;
  out[idx] = f2us(in[((oc * 256 + ic) * 3 + r) * 3 + kw]);
}
// tiled transpose 1024x1024 f32 (wk -> wkT)
__global__ void k_transpose_t(const float* __restrict__ w, float* __restrict__ wt) {
  __shared__ float tile[32][33];
  int x = blockIdx.x * 32 + threadIdx.x;
  for (int j = threadIdx.y; j < 32; j += 8)
    tile[j][threadIdx.x] = w[(size_t)(blockIdx.y * 32 + j) * 1024 + x];
  __syncthreads();
  int x2 = blockIdx.y * 32 + threadIdx.x;
  for (int j = threadIdx.y; j < 32; j += 8)
    wt[(size_t)(blockIdx.x * 32 + j) * 1024 + x2] = tile[threadIdx.x][j];
}

// ---------------- projection + theta ----------------
__global__ void k_proj(const float* __restrict__ boxes, const float* __restrict__ la_m,
                       const float* __restrict__ l2i, const float* __restrict__ aug,
                       const float* __restrict__ tw, const float* __restrict__ tb,
                       float* __restrict__ theta_out, int* __restrict__ valid_out) {
  int t = threadIdx.x;
  if (t >= NIMG) return;
  int n = t / NCAM, cam = t % NCAM;
  int b = n / NBOXB, nb = n % NBOXB;

  float la[4][4];
  for (int r = 0; r < 4; r++)
    for (int c = 0; c < 4; c++) la[r][c] = la_m[b * 16 + r * 4 + c];
  float a00=la[0][0],a01=la[0][1],a02=la[0][2];
  float a10=la[1][0],a11=la[1][1],a12=la[1][2];
  float a20=la[2][0],a21=la[2][1],a22=la[2][2];
  float c00 =  a11*a22 - a12*a21;
  float c01 = -(a10*a22 - a12*a20);
  float c02 =  a10*a21 - a11*a20;
  float det = a00*c00 + a01*c01 + a02*c02;
  float id = 1.0f / det;
  float inv[3][3];
  inv[0][0] = c00*id;                 inv[0][1] = -(a01*a22-a02*a21)*id;  inv[0][2] =  (a01*a12-a02*a11)*id;
  inv[1][0] = c01*id;                 inv[1][1] =  (a00*a22-a02*a20)*id;  inv[1][2] = -(a00*a12-a02*a10)*id;
  inv[2][0] = c02*id;                 inv[2][1] = -(a00*a21-a01*a20)*id;  inv[2][2] =  (a00*a11-a01*a10)*id;

  float bx[9];
  for (int i = 0; i < 9; i++) bx[i] = boxes[(b * NBOXB + nb) * 9 + i];
  float c0[3] = { bx[0]-la[0][3], bx[1]-la[1][3], bx[2]-la[2][3] };
  float c1[3];
  for (int r = 0; r < 3; r++) c1[r] = inv[r][0]*c0[0] + inv[r][1]*c0[1] + inv[r][2]*c0[2];

  const float* M = l2i + (size_t)(b * NCAM + cam) * 16;
  float p[3];
  for (int r = 0; r < 3; r++)
    p[r] = M[r*4+0]*c1[0] + M[r*4+1]*c1[1] + M[r*4+2]*c1[2] + M[r*4+3];
  float z = fminf(fmaxf(p[2], 1e-5f), 100000.0f);
  float x = p[0] / z, y = p[1] / z;
  const float* A = aug + (size_t)(b * NCAM + cam) * 16;
  float u = A[0]*x + A[1]*y + A[2]*z + A[3];
  float v = A[4]*x + A[5]*y + A[6]*z + A[7];

  int on = (v < (float)IMG_H) && (v >= 0.0f) && (u < (float)IMG_W) && (u >= 0.0f);
  float ty = v / (float)IMG_H * 2.0f - 1.0f;
  float tx = u / (float)IMG_W * 2.0f - 1.0f;

  float s[4];
  for (int j = 0; j < 4; j++) {
    float acc = tb[j];
    for (int i = 0; i < 9; i++) acc += tw[j * 9 + i] * bx[i];
    s[j] = tanhf(acc);
  }
  float* o = theta_out + t * 6;
  o[0] = s[0]; o[1] = s[1]; o[2] = tx;
  o[3] = s[2]; o[4] = s[3]; o[5] = ty;
  valid_out[t] = on;
}

// ---------------- zero the crop halo (rows/cols 0,225,226 of 228x228 ch-last buffer) ----------------
#define HALO_PX 1356   // 3*228 + 224*3
__global__ void k_zero_halo(u16x4* __restrict__ c) {
  int t = blockIdx.x * 256 + threadIdx.x;
  int i = t / HALO_PX;
  if (i >= NIMG) return;
  int r = t % HALO_PX;
  int ph, pw;
  if (r < 684) {
    int rr = r / 228;
    ph = (rr == 0) ? 0 : (rr == 1 ? 225 : 226);
    pw = r % 228;
  } else {
    int q = r - 684;
    ph = 1 + q / 3;
    int s = q % 3;
    pw = (s == 0) ? 0 : (s == 1 ? 225 : 226);
  }
  c[(size_t)i * 228 * 228 + ph * 228 + pw] = (u16x4){0, 0, 0, 0};
}

// ---------------- crop sampling -> channel-last halo'd crops [i][228][228][4] bf16 ----------------
__global__ __launch_bounds__(256) void k_sample(const float* __restrict__ imgs,
                                                const float* __restrict__ theta,
                                                u16* __restrict__ crops) {
  int idx = blockIdx.x * 256 + threadIdx.x;   // NIMG*224*224 exactly
  int i = idx / (CROPN * CROPN);
  int rem = idx - i * (CROPN * CROPN);
  int yy = rem / CROPN, xx = rem % CROPN;
  const float* th = theta + i * 6;
  float gx = (2.0f * xx + 1.0f) / (float)CROPN - 1.0f;
  float gy = (2.0f * yy + 1.0f) / (float)CROPN - 1.0f;
  float grid_x = th[0]*gx + th[1]*gy + th[2];
  float grid_y = th[3]*gx + th[4]*gy + th[5];
  float ix = ((grid_x + 1.0f) * (float)IMG_W - 1.0f) * 0.5f;
  float iy = ((grid_y + 1.0f) * (float)IMG_H - 1.0f) * 0.5f;
  float x0 = floorf(ix), y0 = floorf(iy);
  float wx = ix - x0, wy = iy - y0;
  int cam = i % NCAM, b = i / (NBOXB * NCAM);
  const float* base = imgs + (size_t)(b * NCAM + cam) * 3 * IMG_H * IMG_W;

  float xf[2] = { x0, x0 + 1.0f };
  float yf[2] = { y0, y0 + 1.0f };
  float wxa[2] = { 1.0f - wx, wx };
  float wya[2] = { 1.0f - wy, wy };
  int   xi[2], yi[2], vx[2], vy[2];
  for (int j = 0; j < 2; j++) {
    vx[j] = (xf[j] >= 0.0f) && (xf[j] <= (float)(IMG_W - 1));
    vy[j] = (yf[j] >= 0.0f) && (yf[j] <= (float)(IMG_H - 1));
    xi[j] = (int)fminf(fmaxf(xf[j], 0.0f), (float)(IMG_W - 1));
    yi[j] = (int)fminf(fmaxf(yf[j], 0.0f), (float)(IMG_H - 1));
  }
  float res[3];
  #pragma unroll
  for (int ch = 0; ch < 3; ch++) {
    const float* cp = base + (size_t)ch * IMG_H * IMG_W;
    float r = 0.0f;
    #pragma unroll
    for (int jy = 0; jy < 2; jy++)
      #pragma unroll
      for (int jx = 0; jx < 2; jx++) {
        float val = (vx[jx] && vy[jy]) ? cp[yi[jy] * IMG_W + xi[jx]] : 0.0f;
        r += val * wxa[jx] * wya[jy];
      }
    res[ch] = r;
  }
  u16x4 st = { f2us(res[0]), f2us(res[1]), f2us(res[2]), 0 };
  *(u16x4*)(crops + ((size_t)i * 228 * 228 + (size_t)(yy + 1) * 228 + (xx + 1)) * 4) = st;
}

// =========================================================================
// Barrier-free MFMA convs: B-fragments are direct 16-B global loads from
// channel-last activations; A-fragments direct from K-reordered bf16 weights.
// mfma_f32_16x16x32_bf16: A[m=lane&15][k=quad*8+j], B[k][n=lane&15],
// D: col(n)=lane&15, row(m)=quad*4+reg.
// =========================================================================

// ---------------- conv1: 3->64, 7x7 s4, SAME(pad 1,2) via halo buffer, K=224 ----------------
__global__ __launch_bounds__(256) void k_conv1m(const u16* __restrict__ X, // crops_cl
                                                const u16* __restrict__ W, // [64][224]
                                                u16* __restrict__ out) {   // [i][3136][64]
  int blk = blockIdx.x;                 // 384*13
  int i = blk / 13, nb = blk % 13;
  int tid = threadIdx.x, wv = tid >> 6, lane = tid & 63;
  int m = lane & 15, quad = lane >> 4;
  int nbase = nb * 256 + wv * 64;
  int narr[4];
  const u16* bp[4];
  #pragma unroll
  for (int nt = 0; nt < 4; nt++) {
    int n = nbase + nt * 16 + m;
    narr[nt] = n;
    int nc = n < 3136 ? n : 3135;
    int oh = nc / 56, ow = nc - oh * 56;
    bp[nt] = X + ((size_t)i * 51984 + (size_t)(oh * 4) * 228 + ow * 4 + quad * 2) * 4;
  }
  f32x4 acc[4][4];
  #pragma unroll
  for (int t = 0; t < 4; t++)
    #pragma unroll
    for (int nt = 0; nt < 4; nt++) acc[t][nt] = (f32x4){0.f, 0.f, 0.f, 0.f};

  #pragma unroll
  for (int r = 0; r < 7; r++) {
    bf16x8 a[4];
    #pragma unroll
    for (int t = 0; t < 4; t++)
      a[t] = as_b(*(const u16x8*)(W + (t * 16 + m) * 224 + r * 32 + quad * 8));
    #pragma unroll
    for (int nt = 0; nt < 4; nt++) {
      bf16x8 bfr = as_b(*(const u16x8*)(bp[nt] + r * 912));
      #pragma unroll
      for (int t = 0; t < 4; t++)
        acc[t][nt] = __builtin_amdgcn_mfma_f32_16x16x32_bf16(a[t], bfr, acc[t][nt], 0, 0, 0);
    }
  }
  #pragma unroll
  for (int nt = 0; nt < 4; nt++) {
    int n = (narr[nt] & ~15) + m;  // == nbase + nt*16 + m
    if (n < 3136) {
      #pragma unroll
      for (int t = 0; t < 4; t++) {
        u16x4 st;
        #pragma unroll
        for (int r4 = 0; r4 < 4; r4++) st[r4] = f2us(fmaxf(acc[t][nt][r4], 0.f));
        *(u16x4*)(out + ((size_t)i * 3136 + n) * 64 + t * 16 + quad * 4) = st;
      }
    }
  }
}

// ---------------- conv2: 64->256, 3x3 s4, pad 0, K=576 ----------------
__global__ __launch_bounds__(256) void k_conv2m(const u16* __restrict__ X, // c1o [i][3136][64]
                                                const u16* __restrict__ W, // [256][576]
                                                u16* __restrict__ out) {   // [i][196][256]
  int blk = blockIdx.x;                 // 384*4
  int i = blk >> 2, og = blk & 3;
  int oc0 = og * 64;
  int tid = threadIdx.x, wv = tid >> 6, lane = tid & 63;
  int m = lane & 15, quad = lane >> 4;
  int narr[4];
  const u16* bp[4];
  #pragma unroll
  for (int nt = 0; nt < 4; nt++) {
    int n = wv * 64 + nt * 16 + m;
    narr[nt] = n;
    int nc = n < 196 ? n : 195;
    int oh = nc / 14, ow = nc - oh * 14;
    bp[nt] = X + ((size_t)i * 3136 + (size_t)(oh * 4) * 56 + ow * 4) * 64 + quad * 8;
  }
  f32x4 acc[4][4];
  #pragma unroll
  for (int t = 0; t < 4; t++)
    #pragma unroll
    for (int nt = 0; nt < 4; nt++) acc[t][nt] = (f32x4){0.f, 0.f, 0.f, 0.f};

  #pragma unroll
  for (int s = 0; s < 18; s++) {
    const int rk = s >> 1, r = rk / 3, kw = rk % 3;
    const int boff = ((r * 56 + kw) * 64 + (s & 1) * 32);
    bf16x8 a[4];
    #pragma unroll
    for (int t = 0; t < 4; t++)
      a[t] = as_b(*(const u16x8*)(W + (size_t)(oc0 + t * 16 + m) * 576 + s * 32 + quad * 8));
    #pragma unroll
    for (int nt = 0; nt < 4; nt++) {
      bf16x8 bfr = as_b(*(const u16x8*)(bp[nt] + boff));
      #pragma unroll
      for (int t = 0; t < 4; t++)
        acc[t][nt] = __builtin_amdgcn_mfma_f32_16x16x32_bf16(a[t], bfr, acc[t][nt], 0, 0, 0);
    }
  }
  #pragma unroll
  for (int nt = 0; nt < 4; nt++) {
    int n = narr[nt];
    if (n < 196) {
      #pragma unroll
      for (int t = 0; t < 4; t++) {
        u16x4 st;
        #pragma unroll
        for (int r4 = 0; r4 < 4; r4++) st[r4] = f2us(fmaxf(acc[t][nt][r4], 0.f));
        *(u16x4*)(out + ((size_t)i * 196 + n) * 256 + oc0 + t * 16 + quad * 4) = st;
      }
    }
  }
}

// ---------------- conv3: 256->1024, 3x3 s2, pad after=1, K=2304 -> (i,p,oc) f32 ----------------
__global__ __launch_bounds__(256) void k_conv3m(const u16* __restrict__ X, // c2o [i][196][256]
                                                const u16* __restrict__ W, // [1024][2304]
                                                const u16* __restrict__ zbuf,
                                                float* __restrict__ out3) {
  int blk = blockIdx.x;                 // 384*4
  int i = blk >> 2, og = blk & 3;
  int tid = threadIdx.x, wv = tid >> 6, lane = tid & 63;
  int m = lane & 15, quad = lane >> 4;
  int ocw = og * 256 + wv * 64;
  int narr[4], oh2[4], ow2[4];
  #pragma unroll
  for (int nt = 0; nt < 4; nt++) {
    int n = nt * 16 + m;
    narr[nt] = n;
    int nc = n < 49 ? n : 48;
    int oh = nc / 7, ow = nc - oh * 7;
    oh2[nt] = oh * 2; ow2[nt] = ow * 2;
  }
  f32x4 acc[4][4];
  #pragma unroll
  for (int t = 0; t < 4; t++)
    #pragma unroll
    for (int nt = 0; nt < 4; nt++) acc[t][nt] = (f32x4){0.f, 0.f, 0.f, 0.f};

  #pragma unroll
  for (int rk = 0; rk < 9; rk++) {
    const int r = rk / 3, kw = rk % 3;
    const u16* bp[4];
    #pragma unroll
    for (int nt = 0; nt < 4; nt++) {
      int ih = oh2[nt] + r, iw = ow2[nt] + kw;
      bool valid = (narr[nt] < 49) && (ih < 14) && (iw < 14);
      const u16* p = X + ((size_t)i * 196 + ih * 14 + iw) * 256 + quad * 8;
      bp[nt] = valid ? p : (zbuf + quad * 8);
    }
    #pragma unroll
    for (int ic8 = 0; ic8 < 8; ic8++) {
      bf16x8 a[4];
      #pragma unroll
      for (int t = 0; t < 4; t++)
        a[t] = as_b(*(const u16x8*)(W + (size_t)(ocw + t * 16 + m) * 2304 + rk * 256 + ic8 * 32 + quad * 8));
      #pragma unroll
      for (int nt = 0; nt < 4; nt++) {
        bf16x8 bfr = as_b(*(const u16x8*)(bp[nt] + ic8 * 32));
        #pragma unroll
        for (int t = 0; t < 4; t++)
          acc[t][nt] = __builtin_amdgcn_mfma_f32_16x16x32_bf16(a[t], bfr, acc[t][nt], 0, 0, 0);
      }
    }
  }
  #pragma unroll
  for (int nt = 0; nt < 4; nt++) {
    int n = narr[nt];
    if (n < 49) {
      #pragma unroll
      for (int t = 0; t < 4; t++) {
        f32x4 o;
        #pragma unroll
        for (int r4 = 0; r4 < 4; r4++) o[r4] = fmaxf(acc[t][nt][r4], 0.f);
        *(f32x4*)(out3 + ((size_t)i * 49 + n) * DIMN + ocw + t * 16 + quad * 4) = o;
      }
    }
  }
}

// ---------------- tokens: mean + concat + pos ----------------
__global__ __launch_bounds__(256) void k_tok(const float* __restrict__ h,   // (384,49,1024)
                                             const float* __restrict__ pos, // (50,1024)
                                             float* __restrict__ tok) {     // (384,50,1024)
  int blk = blockIdx.x;               // 384*50
  int i = blk / 50, t = blk % 50;
  int d = threadIdx.x * 4;
  float4 val;
  if (t == 0) {
    float sx = 0, sy = 0, sz = 0, sw = 0;
    for (int p = 0; p < 49; p++) {
      float4 v = *(const float4*)(h + ((size_t)i * 49 + p) * DIMN + d);
      sx += v.x; sy += v.y; sz += v.z; sw += v.w;
    }
    const float inv49 = 1.0f / 49.0f;
    val.x = sx * inv49; val.y = sy * inv49; val.z = sz * inv49; val.w = sw * inv49;
  } else {
    val = *(const float4*)(h + ((size_t)i * 49 + (t - 1)) * DIMN + d);
  }
  float4 pe = *(const float4*)(pos + (size_t)t * DIMN + d);
  float4 o; o.x = val.x + pe.x; o.y = val.y + pe.y; o.z = val.z + pe.z; o.w = val.w + pe.w;
  *(float4*)(tok + ((size_t)i * 50 + t) * DIMN + d) = o;
}

// ---------------- batched matvec: out[i,:] = vec[i,:] @ M, 4 images x 512 cols / block ----------------
__global__ __launch_bounds__(256) void k_matvec2(const float* __restrict__ vecs, int vstride,
                                                 const float* __restrict__ M,
                                                 float* __restrict__ out) {
  __shared__ float s_v[4][DIMN];
  int i0 = blockIdx.x * 4;
  int h = blockIdx.y;
  for (int e = threadIdx.x; e < 4 * DIMN; e += 256)
    s_v[e >> 10][e & 1023] = vecs[(size_t)(i0 + (e >> 10)) * vstride + (e & 1023)];
  __syncthreads();
  int d0 = h * 512 + threadIdx.x * 2;
  float2 acc[4] = {{0,0},{0,0},{0,0},{0,0}};
  for (int e = 0; e < DIMN; e++) {
    float2 w = *(const float2*)(M + (size_t)e * DIMN + d0);
    #pragma unroll
    for (int im = 0; im < 4; im++) {
      float x = s_v[im][e];
      acc[im].x += x * w.x; acc[im].y += x * w.y;
    }
  }
  #pragma unroll
  for (int im = 0; im < 4; im++)
    *(float2*)(out + (size_t)(i0 + im) * DIMN + d0) = acc[im];
}

// ---------------- scores + softmax + attn-weighted token mix ----------------
__global__ __launch_bounds__(256) void k_attn(const float* __restrict__ tok,
                                              const float* __restrict__ a1,
                                              float* __restrict__ tvec) {
  __shared__ float s_a[DIMN];
  __shared__ float s_sc[50];
  __shared__ float s_at[50];
  int i = blockIdx.x;
  for (int e = threadIdx.x; e < DIMN; e += 256) s_a[e] = a1[(size_t)i * DIMN + e];
  __syncthreads();
  int wave = threadIdx.x >> 6, lane = threadIdx.x & 63;
  for (int t = wave; t < 50; t += 4) {
    const float* tr = tok + ((size_t)i * 50 + t) * DIMN;
    float p = 0.0f;
    for (int mm = 0; mm < 16; mm++) {
      int e = lane + mm * 64;
      p += tr[e] * s_a[e];
    }
    for (int off = 32; off > 0; off >>= 1) p += __shfl_down(p, off, 64);
    if (lane == 0) s_sc[t] = p * 0.03125f;  // DIM^-0.5
  }
  __syncthreads();
  if (threadIdx.x == 0) {
    float mx = s_sc[0];
    for (int t = 1; t < 50; t++) mx = fmaxf(mx, s_sc[t]);
    float sum = 0.0f;
    for (int t = 0; t < 50; t++) { float ex = expf(s_sc[t] - mx); s_at[t] = ex; sum += ex; }
    float inv = 1.0f / sum;
    for (int t = 0; t < 50; t++) s_at[t] *= inv;
  }
  __syncthreads();
  int d0 = threadIdx.x * 4;
  float ax = 0, ay = 0, az = 0, aw = 0;
  for (int t = 0; t < 50; t++) {
    float at = s_at[t];
    float4 tv = *(const float4*)(tok + ((size_t)i * 50 + t) * DIMN + d0);
    ax += at * tv.x; ay += at * tv.y; az += at * tv.z; aw += at * tv.w;
  }
  float4 o; o.x = ax; o.y = ay; o.z = az; o.w = aw;
  *(float4*)(tvec + (size_t)i * DIMN + d0) = o;
}

// ---------------- final momentum merge ----------------
__global__ __launch_bounds__(256) void k_final(const float* __restrict__ emb,
                                               const int* __restrict__ valid,
                                               const float* __restrict__ bdd,
                                               const float* __restrict__ momp,
                                               float* __restrict__ out) {
  int n = blockIdx.x;
  int d0 = threadIdx.x * 4;
  float mom = momp[0];
  float e[4];
  #pragma unroll
  for (int j = 0; j < 4; j++) e[j] = bdd[d0 + j];
  const int order[6] = {2, 0, 1, 5, 3, 4};
  #pragma unroll
  for (int s = 0; s < 6; s++) {
    int c = order[s];
    int i = n * NCAM + c;
    if (valid[i]) {
      const float* er = emb + (size_t)i * DIMN + d0;
      #pragma unroll
      for (int j = 0; j < 4; j++) e[j] = mom * e[j] + (1.0f - mom) * er[j];
    }
  }
  #pragma unroll
  for (int j = 0; j < 4; j++) out[(size_t)n * DIMN + d0 + j] = e[j];
}

extern "C" void kernel_launch(void* const* d_in, const int* in_sizes, int n_in,
                              void* d_out, int out_size, void* d_ws, size_t ws_size,
                              hipStream_t stream) {
  const float* in_cam = (const float*)d_in[0];
  const float* in_box = (const float*)d_in[1];
  const float* in_aug = (const float*)d_in[2];
  const float* in_la  = (const float*)d_in[3];
  const float* in_l2i = (const float*)d_in[4];
  const float* in_mom = (const float*)d_in[5];
  const float* in_bdd = (const float*)d_in[6];
  const float* in_tw  = (const float*)d_in[7];
  const float* in_tb  = (const float*)d_in[8];
  const float* in_c1  = (const float*)d_in[9];
  const float* in_c2  = (const float*)d_in[10];
  const float* in_c3  = (const float*)d_in[11];
  const float* in_pe  = (const float*)d_in[12];
  const float* in_wq  = (const float*)d_in[13];
  const float* in_wk  = (const float*)d_in[14];
  const float* in_wv  = (const float*)d_in[15];
  const float* in_wo  = (const float*)d_in[16];

  char* base = (char*)d_ws;
  size_t off = 0;
  auto carve = [&](size_t bytes) -> char* {
    char* p = base + off;
    off += (bytes + 255) & ~(size_t)255;
    return p;
  };
  float* theta   = (float*)carve((size_t)NIMG * 6 * 4);
  int*   valid   = (int*)carve((size_t)NIMG * 4);
  float* qbuf    = (float*)carve((size_t)NIMG * DIMN * 4);
  float* a1buf   = (float*)carve((size_t)NIMG * DIMN * 4);
  float* tvbuf   = (float*)carve((size_t)NIMG * DIMN * 4);
  float* ctxbuf  = (float*)carve((size_t)NIMG * DIMN * 4);
  float* embbuf  = (float*)carve((size_t)NIMG * DIMN * 4);
  float* wkT_f   = (float*)carve((size_t)DIMN * DIMN * 4);
  u16*   W1r     = (u16*)carve((size_t)64 * 224 * 2);
  u16*   W2r     = (u16*)carve((size_t)256 * 576 * 2);
  u16*   W3r     = (u16*)carve((size_t)1024 * 2304 * 2);
  u16*   zbuf    = (u16*)carve(512);
  u16*   c2o     = (u16*)carve((size_t)NIMG * 196 * 256 * 2);
  char*  R1      = carve((size_t)NIMG * 228 * 228 * 4 * 2);   // crops_cl / (conv3o + tok)
  u16*   c1o     = (u16*)carve((size_t)NIMG * 3136 * 64 * 2);
  u16*   crops   = (u16*)R1;
  float* conv3o  = (float*)R1;
  float* tok     = (float*)(R1 + (size_t)NIMG * 49 * DIMN * 4);

  k_w1r<<<56, 256, 0, stream>>>(in_c1, W1r);
  k_w2r<<<576, 256, 0, stream>>>(in_c2, W2r);
  k_w3r<<<9216, 256, 0, stream>>>(in_c3, W3r);
  k_transpose_t<<<dim3(32, 32), dim3(32, 8), 0, stream>>>(in_wk, wkT_f);
  hipMemsetAsync(zbuf, 0, 512, stream);

  k_proj<<<1, 384, 0, stream>>>(in_box, in_la, in_l2i, in_aug, in_tw, in_tb, theta, valid);
  k_zero_halo<<<(NIMG * HALO_PX + 255) / 256, 256, 0, stream>>>((u16x4*)crops);
  k_sample<<<(NIMG * CROPN * CROPN) / 256, 256, 0, stream>>>(in_cam, theta, crops);
  k_conv1m<<<NIMG * 13, 256, 0, stream>>>(crops, W1r, c1o);
  k_conv2m<<<NIMG * 4, 256, 0, stream>>>(c1o, W2r, c2o);
  k_conv3m<<<NIMG * 4, 256, 0, stream>>>(c2o, W3r, zbuf, conv3o);
  k_tok<<<NIMG * 50, 256, 0, stream>>>(conv3o, in_pe, tok);
  k_matvec2<<<dim3(96, 2), 256, 0, stream>>>(tok, 50 * DIMN, in_wq, qbuf);
  k_matvec2<<<dim3(96, 2), 256, 0, stream>>>(qbuf, DIMN, wkT_f, a1buf);
  k_attn<<<NIMG, 256, 0, stream>>>(tok, a1buf, tvbuf);
  k_matvec2<<<dim3(96, 2), 256, 0, stream>>>(tvbuf, DIMN, in_wv, ctxbuf);
  k_matvec2<<<dim3(96, 2), 256, 0, stream>>>(ctxbuf, DIMN, in_wo, embbuf);
  k_final<<<NBOX, 256, 0, stream>>>(embbuf, valid, in_bdd, in_mom, (float*)d_out);
}